// Round 1
// baseline (328.404 us; speedup 1.0000x reference)
//
#include <hip/hip_runtime.h>
#include <cstddef>

#define EPS_ 1e-6f

typedef unsigned short u16;
typedef __attribute__((ext_vector_type(8))) short short8;      // bf16x8 MFMA frag
typedef __attribute__((ext_vector_type(8))) unsigned short us8;
typedef __attribute__((ext_vector_type(4))) unsigned short us4;
typedef __attribute__((ext_vector_type(4))) float f32x4;

__device__ __forceinline__ float sigmoidf_(float x){ return 1.0f/(1.0f+__expf(-x)); }
__device__ __forceinline__ u16 f2bf(float x){
  union { __bf16 b; u16 u; } c; c.b = (__bf16)x; return c.u;   // RNE, hw cvt if avail
}
__device__ __forceinline__ float bf2f(u16 u){
  union { unsigned i; float f; } c; c.i = ((unsigned)u) << 16; return c.f;
}
__device__ __forceinline__ us4 cvt4(float4 v){
  us4 h; h[0]=f2bf(v.x); h[1]=f2bf(v.y); h[2]=f2bf(v.z); h[3]=f2bf(v.w); return h;
}

// ---------------------------------------------------------------------------
// WT[e][d] = bf16(W[d][e])
// ---------------------------------------------------------------------------
__global__ __launch_bounds__(256) void prep_w(const float* __restrict__ Wq,
                                              const float* __restrict__ Wk,
                                              u16* __restrict__ WqT,
                                              u16* __restrict__ WkT){
  const int e = blockIdx.x & 255;
  const float* W = (blockIdx.x < 256) ? Wq : Wk;
  u16* WT = (blockIdx.x < 256) ? WqT : WkT;
  const int d = threadIdx.x;
  WT[e*256 + d] = f2bf(W[d*256 + e]);
}

// ---------------------------------------------------------------------------
// phi_both v4: 32-row tiles (was 64). Rationale: v3's acc(64)+Bfr(32)+af(16)
// + staging regs blew the 128-VGPR cap of launch_bounds(256,4) -> compiler
// serialized the staging loads (repeated HBM latency exposure; all pipes <25%).
// 32-row tile: acc[2][4]=32 regs, staging=8 float4=32 regs, peak ~100 < 128.
// Grid 4096 blocks -> 4 launch rounds -> cross-block phase staggering.
// LDS ~17 KB.
// ---------------------------------------------------------------------------
__global__ __launch_bounds__(256, 4) void phi_both(
    const float* __restrict__ Q, const float* __restrict__ K,
    const u16* __restrict__ WqT, const u16* __restrict__ WkT,
    const float* __restrict__ bq, const float* __restrict__ bk,
    u16* __restrict__ phi_q, u16* __restrict__ phi_kT,
    float* __restrict__ rowsum, float* __restrict__ colsum)
{
  __shared__ union {
    u16 A[32][264];     // [row][k] staging, 16896 B (row 528 B = 16B mult)
    u16 S[32][264];     // !trans epilogue [row][f]
    u16 T2[128][48];    // trans epilogue half-pass [f&127][n 32], 96 B rows (16B mult)
  } sh;

  const int t = threadIdx.x;
  const int l = t & 63;
  const int wf = t >> 6;          // f-quarter
  const int i16 = l & 15, q = l >> 4;
  const int row0 = blockIdx.x * 32;
  const bool trans = (blockIdx.z != 0);

  const float* X    = trans ? K   : Q;
  const u16*  WT    = trans ? WkT : WqT;
  const float* bias = trans ? bk  : bq;

  // ---- stage X tile (32x256 f32 -> bf16 LDS): 8 float4/thread, ALL in flight ----
  {
    const int r0 = t >> 4;        // 0..15
    const int c0 = t & 15;        // float4 col
    float4 v[8];
    #pragma unroll
    for (int p = 0; p < 8; p++) {
      const int row = r0 + 16*(p & 1);
      const int k4  = c0 + 16*(p >> 1);
      v[p] = *(const float4*)&X[(size_t)(row0 + row)*256 + k4*4];
    }
    #pragma unroll
    for (int p = 0; p < 8; p++) {
      const int row = r0 + 16*(p & 1);
      const int k4  = c0 + 16*(p >> 1);
      *(us4*)&sh.A[row][k4*4] = cvt4(v[p]);
    }
  }
  __syncthreads();

  // ---- K loop: 8 steps, no barriers ----
  f32x4 acc[2][4];
  #pragma unroll
  for (int i=0;i<2;i++)
    #pragma unroll
    for (int j=0;j<4;j++) acc[i][j] = (f32x4){0.f,0.f,0.f,0.f};

  const u16* wb = WT + (size_t)(wf*64 + i16)*256 + q*8;
  short8 Bfr[2][4];
  #pragma unroll
  for (int fi=0;fi<4;fi++) Bfr[0][fi] = *(const short8*)&wb[fi*4096];

  #pragma unroll
  for (int it = 0; it < 8; it++) {
    if (it < 7) {
      #pragma unroll
      for (int fi=0;fi<4;fi++)
        Bfr[(it+1)&1][fi] = *(const short8*)&wb[fi*4096 + (it+1)*32];
    }
    short8 af[2];
    #pragma unroll
    for (int mi=0;mi<2;mi++)
      af[mi] = *(const short8*)&sh.A[mi*16 + i16][it*32 + q*8];
    #pragma unroll
    for (int mi=0;mi<2;mi++)
      #pragma unroll
      for (int fi=0;fi<4;fi++)
        acc[mi][fi] = __builtin_amdgcn_mfma_f32_16x16x32_bf16(af[mi], Bfr[it&1][fi], acc[mi][fi], 0,0,0);
  }

  float bv[4];
  #pragma unroll
  for (int fi=0;fi<4;fi++) bv[fi] = bias[wf*64 + fi*16 + i16];

  __syncthreads();   // A reads done; LDS reusable

  if (!trans) {
    #pragma unroll
    for (int mi=0;mi<2;mi++) {
      float rsub[4] = {0.f,0.f,0.f,0.f};
      #pragma unroll
      for (int fi=0;fi<4;fi++) {
        #pragma unroll
        for (int r=0;r<4;r++) {
          float ph = sigmoidf_(acc[mi][fi][r] + bv[fi]);
          rsub[r] += ph;
          sh.S[mi*16 + q*4 + r][wf*64 + fi*16 + i16] = f2bf(ph);
        }
      }
      #pragma unroll
      for (int r=0;r<4;r++) {
        float s = rsub[r];
        s += __shfl_xor(s,1); s += __shfl_xor(s,2); s += __shfl_xor(s,4); s += __shfl_xor(s,8);
        if (i16 == 0) atomicAdd(&rowsum[row0 + mi*16 + q*4 + r], s);
      }
    }
    __syncthreads();
    const size_t gbase = (size_t)row0 * 256;
    #pragma unroll
    for (int j=0;j<4;j++) {
      const int g = (j*256 + t) * 8;       // u16 index in 8192
      *(us8*)&phi_q[gbase + g] = *(const us8*)&sh.S[g >> 8][g & 255];
    }
  } else {
    const int b      = row0 >> 12;
    const int nchunk = (row0 & 4095) >> 6;
    const int nhalf  = (row0 >> 5) & 1;    // which 32-row half of the n64 chunk
    #pragma unroll
    for (int h = 0; h < 2; h++) {
      if ((wf >> 1) == h) {
        #pragma unroll
        for (int fi=0;fi<4;fi++) {
          float cp = 0.f;
          #pragma unroll
          for (int mi=0;mi<2;mi++) {
            us4 o;
            #pragma unroll
            for (int r=0;r<4;r++) {
              float ph = sigmoidf_(acc[mi][fi][r] + bv[fi]);
              cp += ph;
              o[r] = f2bf(ph);
            }
            *(us4*)&sh.T2[(wf*64 + fi*16 + i16) & 127][mi*16 + q*4] = o;
          }
          cp += __shfl_xor(cp,16); cp += __shfl_xor(cp,32);   // reduce over q
          if (l < 16) atomicAdd(&colsum[b*256 + wf*64 + fi*16 + l], cp);
        }
      }
      __syncthreads();
      // store [f 128][n 32] into tiled phi_kT [b][nchunk][f][n64] at nhalf*32
      const size_t gb = ((size_t)(b*64 + nchunk)*256 + h*128)*64 + nhalf*32;
      #pragma unroll
      for (int j=0;j<2;j++) {
        const int g = (j*256 + t) * 8;     // u16 index in 4096
        const int f = g >> 5, n = g & 31;
        *(us8*)&phi_kT[gb + (size_t)f*64 + n] = *(const us8*)&sh.T2[f][n];
      }
      __syncthreads();
    }
  }
}

// ---------------------------------------------------------------------------
// KV partials: grid (e0/64, nc 0..15, b). Block: d=256 x e=64, 4 chunks of 64 n.
// phi_kT is tiled [b][nchunk][d][n64] -> perfectly contiguous 32 KB chunk reads.
// E[n,e] = exp(phi_k*inv_cs*V); partsT[nc][b][e][d] bf16 (us4-packed along d);
// denom f32 atomics.
// ---------------------------------------------------------------------------
__global__ __launch_bounds__(256) void kv_kernel(const u16* __restrict__ phi_kT,
    const float* __restrict__ V, const float* __restrict__ colsum,
    u16* __restrict__ partsT, float* __restrict__ denom)
{
  __shared__ u16 phiT_lds[256][72];   // [d][n 64]
  __shared__ u16 E_lds[64][72];       // [e][n 64]

  const int t = threadIdx.x;
  const int l = t & 63;
  const int w = t >> 6;
  const int e0 = blockIdx.x * 64;
  const int nc = blockIdx.y;
  const int b  = blockIdx.z;
  const int i16 = l & 15, q = l >> 4;

  const int sd = t >> 3;          // staging d-base (0..31)
  const int sn = (t & 7) * 8;     // staging n-offset

  const size_t cbase = (size_t)(b*64 + nc*4) * 256 * 64;   // u16 idx of chunk 0

  us8  rA[8];
  float rV[16];
  #pragma unroll
  for (int p=0;p<8;p++)
    rA[p] = *(const us8*)&phi_kT[cbase + (size_t)(sd + 32*p)*64 + sn];
  #pragma unroll
  for (int j=0;j<16;j++)
    rV[j] = V[(size_t)(b*4096 + nc*256 + w*16 + j)*256 + e0 + l];

  const float inv_cs = 1.0f / (colsum[b*256 + e0 + l] + EPS_);
  float dsum = 0.f;

  f32x4 acc[4][4];
  #pragma unroll
  for (int i=0;i<4;i++)
    #pragma unroll
    for (int j=0;j<4;j++) acc[i][j] = (f32x4){0.f,0.f,0.f,0.f};

  for (int c = 0; c < 4; c++) {
    #pragma unroll
    for (int p=0;p<8;p++) *(us8*)&phiT_lds[sd + 32*p][sn] = rA[p];
    __syncthreads();
    if (c < 3) {
      const size_t nb = cbase + (size_t)(c+1)*16384;
      #pragma unroll
      for (int p=0;p<8;p++)
        rA[p] = *(const us8*)&phi_kT[nb + (size_t)(sd + 32*p)*64 + sn];
    }
    us8 pv0 = *(const us8*)&phiT_lds[e0 + l][w*16];
    us8 pv1 = *(const us8*)&phiT_lds[e0 + l][w*16 + 8];
    us8 ev0, ev1;
    #pragma unroll
    for (int j=0;j<8;j++) {
      float ef = __expf(bf2f(pv0[j]) * inv_cs * rV[j]);
      dsum += ef; ev0[j] = f2bf(ef);
    }
    #pragma unroll
    for (int j=0;j<8;j++) {
      float ef = __expf(bf2f(pv1[j]) * inv_cs * rV[8+j]);
      dsum += ef; ev1[j] = f2bf(ef);
    }
    *(us8*)&E_lds[l][w*16]     = ev0;
    *(us8*)&E_lds[l][w*16 + 8] = ev1;
    if (c < 3) {
      #pragma unroll
      for (int j=0;j<16;j++)
        rV[j] = V[(size_t)(b*4096 + nc*256 + (c+1)*64 + w*16 + j)*256 + e0 + l];
    }
    __syncthreads();
    #pragma unroll
    for (int kk=0;kk<2;kk++){
      const int ko = kk*32 + q*8;
      short8 af[4], bfr[4];
      #pragma unroll
      for (int mi=0;mi<4;mi++) af[mi]  = *(const short8*)&phiT_lds[w*64 + mi*16 + i16][ko];
      #pragma unroll
      for (int ei=0;ei<4;ei++) bfr[ei] = *(const short8*)&E_lds[ei*16 + i16][ko];
      #pragma unroll
      for (int mi=0;mi<4;mi++)
        #pragma unroll
        for (int ei=0;ei<4;ei++)
          acc[mi][ei] = __builtin_amdgcn_mfma_f32_16x16x32_bf16(af[mi], bfr[ei], acc[mi][ei],0,0,0);
    }
    __syncthreads();
  }

  atomicAdd(&denom[b*256 + e0 + l], dsum);

  // partsT[nc][b][e][d]: acc D-layout row=d=q*4+r (r contiguous) -> us4 along d
  u16* slice = partsT + (size_t)(nc*16 + b) * 65536;
  #pragma unroll
  for (int mi=0;mi<4;mi++)
    #pragma unroll
    for (int ei=0;ei<4;ei++) {
      us4 o;
      #pragma unroll
      for (int r=0;r<4;r++) o[r] = f2bf(acc[mi][ei][r]);
      *(us4*)&slice[(size_t)(e0 + ei*16 + i16)*256 + w*64 + mi*16 + q*4] = o;
    }
}

// ---------------------------------------------------------------------------
// KV_nT[b][e][d] = bf16( (sum_nc partsT[nc][b][e][d]) / denom[b][e] )
// Pure streaming: no LDS, us4 vector loads, 4 e-rows per block.
// ---------------------------------------------------------------------------
__global__ __launch_bounds__(256) void kv_norm(const u16* __restrict__ partsT,
    const float* __restrict__ denom, u16* __restrict__ KV_nT)
{
  const int t = threadIdx.x;
  const int b = blockIdx.y;
  const size_t idx = (size_t)blockIdx.x * 1024 + t*4;   // u16 index in [e][d] plane
  const int e = (int)(idx >> 8);
  const float dn = denom[b*256 + e];
  float s0=0.f,s1=0.f,s2=0.f,s3=0.f;
  #pragma unroll 4
  for (int nc=0;nc<16;nc++){
    us4 v = *(const us4*)&partsT[(size_t)(nc*16 + b)*65536 + idx];
    s0+=bf2f(v[0]); s1+=bf2f(v[1]); s2+=bf2f(v[2]); s3+=bf2f(v[3]);
  }
  us4 o; o[0]=f2bf(s0/dn); o[1]=f2bf(s1/dn); o[2]=f2bf(s2/dn); o[3]=f2bf(s3/dn);
  *(us4*)&KV_nT[(size_t)b*65536 + idx] = o;
}

// ---------------------------------------------------------------------------
// out[b,n,e] = sigmoid(rs)/(rs+eps) * sum_d phi_q[n,d] * KV_n[d,e]
// v2: 32-row tiles (same reg-pressure fix as phi_both v4): acc[2][4]=32 regs,
// stage 4x us8 in one batch. Grid 2048 blocks.
// ---------------------------------------------------------------------------
__global__ __launch_bounds__(256, 4) void out_gemm(const u16* __restrict__ phi_q,
    const u16* __restrict__ KV_nT, const float* __restrict__ rowsum,
    float* __restrict__ outp)
{
  __shared__ u16 A_lds[32][264];
  __shared__ float rs_lds[32];

  const int t = threadIdx.x;
  const int l = t & 63;
  const int we = t >> 6;
  const int i16 = l & 15, q = l >> 4;
  const int n0 = blockIdx.x * 32;
  const int b  = blockIdx.y;

  if (t < 32) rs_lds[t] = rowsum[b*4096 + n0 + t];

  {
    const size_t gbase = (size_t)(b*4096 + n0) * 256;
    us8 v[4];
    #pragma unroll
    for (int j=0;j<4;j++)
      v[j] = *(const us8*)&phi_q[gbase + (size_t)(j*256 + t)*8];
    #pragma unroll
    for (int j=0;j<4;j++) {
      const int g = (j*256 + t) * 8;
      *(us8*)&A_lds[g >> 8][g & 255] = v[j];
    }
  }
  __syncthreads();

  f32x4 acc[2][4];
  #pragma unroll
  for (int i=0;i<2;i++)
    #pragma unroll
    for (int j=0;j<4;j++) acc[i][j] = (f32x4){0.f,0.f,0.f,0.f};

  const u16* kb = KV_nT + (size_t)(b*256 + we*64 + i16)*256 + q*8;
  short8 Bfr[2][4];
  #pragma unroll
  for (int ei=0;ei<4;ei++) Bfr[0][ei] = *(const short8*)&kb[ei*4096];

  #pragma unroll
  for (int it=0; it<8; it++){
    if (it < 7) {
      #pragma unroll
      for (int ei=0;ei<4;ei++)
        Bfr[(it+1)&1][ei] = *(const short8*)&kb[ei*4096 + (it+1)*32];
    }
    short8 af[2];
    #pragma unroll
    for (int mi=0;mi<2;mi++)
      af[mi] = *(const short8*)&A_lds[mi*16 + i16][it*32 + q*8];
    #pragma unroll
    for (int mi=0;mi<2;mi++)
      #pragma unroll
      for (int ei=0;ei<4;ei++)
        acc[mi][ei] = __builtin_amdgcn_mfma_f32_16x16x32_bf16(af[mi], Bfr[it&1][ei], acc[mi][ei],0,0,0);
  }

  #pragma unroll
  for (int mi=0;mi<2;mi++){
    #pragma unroll
    for (int r=0;r<4;r++){
      const int nl = mi*16 + q*4 + r;
      const float rs = rs_lds[nl];
      const float gate = sigmoidf_(rs) / (rs + EPS_);
      #pragma unroll
      for (int ei=0;ei<4;ei++)
        outp[((size_t)(b*4096 + n0 + nl))*256 + we*64 + ei*16 + i16] = gate*acc[mi][ei][r];
    }
  }
}

extern "C" void kernel_launch(void* const* d_in, const int* in_sizes, int n_in,
                              void* d_out, int out_size, void* d_ws, size_t ws_size,
                              hipStream_t stream) {
  const float* Q  = (const float*)d_in[0];
  const float* K  = (const float*)d_in[1];
  const float* V  = (const float*)d_in[2];
  const float* Wq = (const float*)d_in[3];
  const float* bq = (const float*)d_in[4];
  const float* Wk = (const float*)d_in[5];
  const float* bk = (const float*)d_in[6];
  float* out = (float*)d_out;

  u16* phi_q  = (u16*)d_ws;                 // 16,777,216 bf16 [b][n][d]
  u16* phi_kT = phi_q + 16777216;           // 16,777,216 bf16 TILED [b][nchunk][d][n64]
  u16* WqT    = phi_kT + 16777216;          // 65,536
  u16* WkT    = WqT + 65536;                // 65,536
  float* colsum = (float*)(WkT + 65536);    // 4096
  float* denom  = colsum + 4096;            // 4096
  float* rowsum = denom + 4096;             // 65,536
  u16* partsT = (u16*)(rowsum + 65536);     // 16*16*65536 bf16 (33.5 MB) [nc][b][e][d]
  u16* KV_nT  = partsT + 16777216;          // 1,048,576 bf16 [b][e][d]

  hipMemsetAsync(colsum, 0, (4096 + 4096 + 65536) * sizeof(float), stream);

  prep_w<<<dim3(512), 256, 0, stream>>>(Wq, Wk, WqT, WkT);
  phi_both<<<dim3(2048, 1, 2), 256, 0, stream>>>(Q, K, WqT, WkT, bq, bk,
                                                 phi_q, phi_kT, rowsum, colsum);
  kv_kernel<<<dim3(4, 16, 16), 256, 0, stream>>>(phi_kT, V, colsum, partsT, denom);
  kv_norm<<<dim3(64, 16), 256, 0, stream>>>(partsT, denom, KV_nT);
  out_gemm<<<dim3(128, 16), 256, 0, stream>>>(phi_q, KV_nT, rowsum, out);
}

// Round 2
// 300.435 us; speedup vs baseline: 1.0931x; 1.0931x over previous
//
#include <hip/hip_runtime.h>
#include <cstddef>

#define EPS_ 1e-6f

typedef unsigned short u16;
typedef __attribute__((ext_vector_type(8))) short short8;      // bf16x8 MFMA frag
typedef __attribute__((ext_vector_type(8))) unsigned short us8;
typedef __attribute__((ext_vector_type(4))) unsigned short us4;
typedef __attribute__((ext_vector_type(4))) float f32x4;

__device__ __forceinline__ float sigmoidf_(float x){ return 1.0f/(1.0f+__expf(-x)); }
// fast sigmoid: v_rcp_f32 (~1 ulp) instead of IEEE divide (~10 inst). Used only
// where the result is immediately rounded to bf16.
__device__ __forceinline__ float sigmoidf_fast(float x){
  return __builtin_amdgcn_rcpf(1.0f+__expf(-x));
}
__device__ __forceinline__ u16 f2bf(float x){
  union { __bf16 b; u16 u; } c; c.b = (__bf16)x; return c.u;   // RNE, hw cvt if avail
}
__device__ __forceinline__ float bf2f(u16 u){
  union { unsigned i; float f; } c; c.i = ((unsigned)u) << 16; return c.f;
}
__device__ __forceinline__ us4 cvt4(float4 v){
  us4 h; h[0]=f2bf(v.x); h[1]=f2bf(v.y); h[2]=f2bf(v.z); h[3]=f2bf(v.w); return h;
}

// ---------------------------------------------------------------------------
// WT[e][d] = bf16(W[d][e])
// ---------------------------------------------------------------------------
__global__ __launch_bounds__(256) void prep_w(const float* __restrict__ Wq,
                                              const float* __restrict__ Wk,
                                              u16* __restrict__ WqT,
                                              u16* __restrict__ WkT){
  const int e = blockIdx.x & 255;
  const float* W = (blockIdx.x < 256) ? Wq : Wk;
  u16* WT = (blockIdx.x < 256) ? WqT : WkT;
  const int d = threadIdx.x;
  WT[e*256 + d] = f2bf(W[d*256 + e]);
}

// ---------------------------------------------------------------------------
// phi_both v5: 64-row tile (v3 structure — v4's 32-row regressed), but
// launch_bounds(256,3). v3 already ran at 3 blocks/CU (occ 37%); the (256,4)
// bound capped regs at 128 = exactly acc(64)+Bfr(32)+af(16)+misc, leaving no
// room to pipeline. With ~170-reg budget:
//   - W prefetch 2-deep (3-slot rotation, issue it+2) -> cover ~260cy >= L2 lat
//   - A-stage loads batched 8-at-a-time -> HBM latency paid ~2x not ~4x
//   - epilogue sigmoid uses v_rcp instead of IEEE div (result stored as bf16)
// ---------------------------------------------------------------------------
__global__ __launch_bounds__(256, 3) void phi_both(
    const float* __restrict__ Q, const float* __restrict__ K,
    const u16* __restrict__ WqT, const u16* __restrict__ WkT,
    const float* __restrict__ bq, const float* __restrict__ bk,
    u16* __restrict__ phi_q, u16* __restrict__ phi_kT,
    float* __restrict__ rowsum, float* __restrict__ colsum)
{
  __shared__ union {
    u16 A[64][264];     // [row][k] staging, 33792 B (row 528 B = 16B mult)
    u16 S[64][264];     // !trans epilogue [row][f]
    u16 T2[128][136];   // trans epilogue half-pass [f&127][n], 34816 B
  } sh;

  const int t = threadIdx.x;
  const int l = t & 63;
  const int wf = t >> 6;          // f-quarter
  const int i16 = l & 15, q = l >> 4;
  const int row0 = blockIdx.x * 64;
  const bool trans = (blockIdx.z != 0);

  const float* X    = trans ? K   : Q;
  const u16*  WT    = trans ? WkT : WqT;
  const float* bias = trans ? bk  : bq;

  // ---- stage X tile (64x256 f32 -> bf16 LDS), 2 batches of 8 float4 ----
  {
    const int r0 = t >> 4;        // 0..15
    const int c0 = t & 15;        // float4 col
    #pragma unroll
    for (int half = 0; half < 2; half++) {
      float4 v[8];
      #pragma unroll
      for (int p = 0; p < 8; p++) {
        const int row = r0 + 16*(half*2 + (p >> 2));
        const int k4  = c0 + 16*(p & 3);
        v[p] = *(const float4*)&X[(size_t)(row0 + row)*256 + k4*4];
      }
      #pragma unroll
      for (int p = 0; p < 8; p++) {
        const int row = r0 + 16*(half*2 + (p >> 2));
        const int k4  = c0 + 16*(p & 3);
        *(us4*)&sh.A[row][k4*4] = cvt4(v[p]);
      }
    }
  }
  __syncthreads();

  // ---- K loop: 8 steps, no barriers, 2-deep W prefetch ----
  f32x4 acc[4][4];
  #pragma unroll
  for (int i=0;i<4;i++)
    #pragma unroll
    for (int j=0;j<4;j++) acc[i][j] = (f32x4){0.f,0.f,0.f,0.f};

  const u16* wb = WT + (size_t)(wf*64 + i16)*256 + q*8;
  short8 Bfr[3][4];
  #pragma unroll
  for (int fi=0;fi<4;fi++) Bfr[0][fi] = *(const short8*)&wb[fi*4096];
  #pragma unroll
  for (int fi=0;fi<4;fi++) Bfr[1][fi] = *(const short8*)&wb[fi*4096 + 32];

  #pragma unroll
  for (int it = 0; it < 8; it++) {
    if (it < 6) {
      #pragma unroll
      for (int fi=0;fi<4;fi++)
        Bfr[(it+2)%3][fi] = *(const short8*)&wb[fi*4096 + (it+2)*32];
    }
    short8 af[4];
    #pragma unroll
    for (int mi=0;mi<4;mi++)
      af[mi] = *(const short8*)&sh.A[mi*16 + i16][it*32 + q*8];
    #pragma unroll
    for (int mi=0;mi<4;mi++)
      #pragma unroll
      for (int fi=0;fi<4;fi++)
        acc[mi][fi] = __builtin_amdgcn_mfma_f32_16x16x32_bf16(af[mi], Bfr[it%3][fi], acc[mi][fi], 0,0,0);
  }

  float bv[4];
  #pragma unroll
  for (int fi=0;fi<4;fi++) bv[fi] = bias[wf*64 + fi*16 + i16];

  __syncthreads();   // A reads done; LDS reusable

  if (!trans) {
    #pragma unroll
    for (int mi=0;mi<4;mi++) {
      float rsub[4] = {0.f,0.f,0.f,0.f};
      #pragma unroll
      for (int fi=0;fi<4;fi++) {
        #pragma unroll
        for (int r=0;r<4;r++) {
          float ph = sigmoidf_fast(acc[mi][fi][r] + bv[fi]);
          rsub[r] += ph;
          sh.S[mi*16 + q*4 + r][wf*64 + fi*16 + i16] = f2bf(ph);
        }
      }
      #pragma unroll
      for (int r=0;r<4;r++) {
        float s = rsub[r];
        s += __shfl_xor(s,1); s += __shfl_xor(s,2); s += __shfl_xor(s,4); s += __shfl_xor(s,8);
        if (i16 == 0) atomicAdd(&rowsum[row0 + mi*16 + q*4 + r], s);
      }
    }
    __syncthreads();
    const size_t gbase = (size_t)row0 * 256;
    #pragma unroll
    for (int j=0;j<8;j++) {
      const int g = (j*256 + t) * 8;       // u16 index in 16384
      *(us8*)&phi_q[gbase + g] = *(const us8*)&sh.S[g >> 8][g & 255];
    }
  } else {
    const int b      = row0 >> 12;
    const int nchunk = (row0 & 4095) >> 6;
    #pragma unroll
    for (int h = 0; h < 2; h++) {
      if ((wf >> 1) == h) {
        #pragma unroll
        for (int fi=0;fi<4;fi++) {
          float cp = 0.f;
          #pragma unroll
          for (int mi=0;mi<4;mi++) {
            #pragma unroll
            for (int r=0;r<4;r++) {
              float ph = sigmoidf_fast(acc[mi][fi][r] + bv[fi]);
              cp += ph;
              sh.T2[(wf*64 + fi*16 + i16) & 127][mi*16 + q*4 + r] = f2bf(ph);
            }
          }
          cp += __shfl_xor(cp,16); cp += __shfl_xor(cp,32);   // reduce over q
          if (l < 16) atomicAdd(&colsum[b*256 + wf*64 + fi*16 + l], cp);
        }
      }
      __syncthreads();
      // contiguous 16 KB tile store: [f 128][n 64] u16
      const size_t gb = ((size_t)(b*64 + nchunk)*256 + h*128) * 64;
      #pragma unroll
      for (int j=0;j<4;j++) {
        const int g = (j*256 + t) * 8;     // u16 index in 8192
        *(us8*)&phi_kT[gb + g] = *(const us8*)&sh.T2[g >> 6][g & 63];
      }
      __syncthreads();
    }
  }
}

// ---------------------------------------------------------------------------
// KV partials: grid (e0/64, nc 0..15, b). Block: d=256 x e=64, 4 chunks of 64 n.
// phi_kT is tiled [b][nchunk][d][n64] -> perfectly contiguous 32 KB chunk reads.
// E[n,e] = exp(phi_k*inv_cs*V); partsT[nc][b][e][d] bf16 (us4-packed along d);
// denom f32 atomics.
// ---------------------------------------------------------------------------
__global__ __launch_bounds__(256) void kv_kernel(const u16* __restrict__ phi_kT,
    const float* __restrict__ V, const float* __restrict__ colsum,
    u16* __restrict__ partsT, float* __restrict__ denom)
{
  __shared__ u16 phiT_lds[256][72];   // [d][n 64]
  __shared__ u16 E_lds[64][72];       // [e][n 64]

  const int t = threadIdx.x;
  const int l = t & 63;
  const int w = t >> 6;
  const int e0 = blockIdx.x * 64;
  const int nc = blockIdx.y;
  const int b  = blockIdx.z;
  const int i16 = l & 15, q = l >> 4;

  const int sd = t >> 3;          // staging d-base (0..31)
  const int sn = (t & 7) * 8;     // staging n-offset

  const size_t cbase = (size_t)(b*64 + nc*4) * 256 * 64;   // u16 idx of chunk 0

  us8  rA[8];
  float rV[16];
  #pragma unroll
  for (int p=0;p<8;p++)
    rA[p] = *(const us8*)&phi_kT[cbase + (size_t)(sd + 32*p)*64 + sn];
  #pragma unroll
  for (int j=0;j<16;j++)
    rV[j] = V[(size_t)(b*4096 + nc*256 + w*16 + j)*256 + e0 + l];

  const float inv_cs = 1.0f / (colsum[b*256 + e0 + l] + EPS_);
  float dsum = 0.f;

  f32x4 acc[4][4];
  #pragma unroll
  for (int i=0;i<4;i++)
    #pragma unroll
    for (int j=0;j<4;j++) acc[i][j] = (f32x4){0.f,0.f,0.f,0.f};

  for (int c = 0; c < 4; c++) {
    #pragma unroll
    for (int p=0;p<8;p++) *(us8*)&phiT_lds[sd + 32*p][sn] = rA[p];
    __syncthreads();
    if (c < 3) {
      const size_t nb = cbase + (size_t)(c+1)*16384;
      #pragma unroll
      for (int p=0;p<8;p++)
        rA[p] = *(const us8*)&phi_kT[nb + (size_t)(sd + 32*p)*64 + sn];
    }
    us8 pv0 = *(const us8*)&phiT_lds[e0 + l][w*16];
    us8 pv1 = *(const us8*)&phiT_lds[e0 + l][w*16 + 8];
    us8 ev0, ev1;
    #pragma unroll
    for (int j=0;j<8;j++) {
      float ef = __expf(bf2f(pv0[j]) * inv_cs * rV[j]);
      dsum += ef; ev0[j] = f2bf(ef);
    }
    #pragma unroll
    for (int j=0;j<8;j++) {
      float ef = __expf(bf2f(pv1[j]) * inv_cs * rV[8+j]);
      dsum += ef; ev1[j] = f2bf(ef);
    }
    *(us8*)&E_lds[l][w*16]     = ev0;
    *(us8*)&E_lds[l][w*16 + 8] = ev1;
    if (c < 3) {
      #pragma unroll
      for (int j=0;j<16;j++)
        rV[j] = V[(size_t)(b*4096 + nc*256 + (c+1)*64 + w*16 + j)*256 + e0 + l];
    }
    __syncthreads();
    #pragma unroll
    for (int kk=0;kk<2;kk++){
      const int ko = kk*32 + q*8;
      short8 af[4], bfr[4];
      #pragma unroll
      for (int mi=0;mi<4;mi++) af[mi]  = *(const short8*)&phiT_lds[w*64 + mi*16 + i16][ko];
      #pragma unroll
      for (int ei=0;ei<4;ei++) bfr[ei] = *(const short8*)&E_lds[ei*16 + i16][ko];
      #pragma unroll
      for (int mi=0;mi<4;mi++)
        #pragma unroll
        for (int ei=0;ei<4;ei++)
          acc[mi][ei] = __builtin_amdgcn_mfma_f32_16x16x32_bf16(af[mi], bfr[ei], acc[mi][ei],0,0,0);
    }
    __syncthreads();
  }

  atomicAdd(&denom[b*256 + e0 + l], dsum);

  // partsT[nc][b][e][d]: acc D-layout row=d=q*4+r (r contiguous) -> us4 along d
  u16* slice = partsT + (size_t)(nc*16 + b) * 65536;
  #pragma unroll
  for (int mi=0;mi<4;mi++)
    #pragma unroll
    for (int ei=0;ei<4;ei++) {
      us4 o;
      #pragma unroll
      for (int r=0;r<4;r++) o[r] = f2bf(acc[mi][ei][r]);
      *(us4*)&slice[(size_t)(e0 + ei*16 + i16)*256 + w*64 + mi*16 + q*4] = o;
    }
}

// ---------------------------------------------------------------------------
// KV_nT[b][e][d] = bf16( (sum_nc partsT[nc][b][e][d]) / denom[b][e] )
// Pure streaming: no LDS, us4 vector loads, 4 e-rows per block.
// ---------------------------------------------------------------------------
__global__ __launch_bounds__(256) void kv_norm(const u16* __restrict__ partsT,
    const float* __restrict__ denom, u16* __restrict__ KV_nT)
{
  const int t = threadIdx.x;
  const int b = blockIdx.y;
  const size_t idx = (size_t)blockIdx.x * 1024 + t*4;   // u16 index in [e][d] plane
  const int e = (int)(idx >> 8);
  const float dn = denom[b*256 + e];
  float s0=0.f,s1=0.f,s2=0.f,s3=0.f;
  #pragma unroll 4
  for (int nc=0;nc<16;nc++){
    us4 v = *(const us4*)&partsT[(size_t)(nc*16 + b)*65536 + idx];
    s0+=bf2f(v[0]); s1+=bf2f(v[1]); s2+=bf2f(v[2]); s3+=bf2f(v[3]);
  }
  us4 o; o[0]=f2bf(s0/dn); o[1]=f2bf(s1/dn); o[2]=f2bf(s2/dn); o[3]=f2bf(s3/dn);
  *(us4*)&KV_nT[(size_t)b*65536 + idx] = o;
}

// ---------------------------------------------------------------------------
// out[b,n,e] = sigmoid(rs)/(rs+eps) * sum_d phi_q[n,d] * KV_n[d,e]
// v3: 64n x 256e tile (v1 structure), launch_bounds(256,3), 2-deep B prefetch,
// batched A staging. Same pipelining rationale as phi_both v5.
// ---------------------------------------------------------------------------
__global__ __launch_bounds__(256, 3) void out_gemm(const u16* __restrict__ phi_q,
    const u16* __restrict__ KV_nT, const float* __restrict__ rowsum,
    float* __restrict__ outp)
{
  __shared__ u16 A_lds[64][264];
  __shared__ float rs_lds[64];

  const int t = threadIdx.x;
  const int l = t & 63;
  const int we = t >> 6;
  const int i16 = l & 15, q = l >> 4;
  const int n0 = blockIdx.x * 64;
  const int b  = blockIdx.y;

  if (t < 64) rs_lds[t] = rowsum[b*4096 + n0 + t];

  {
    const size_t gbase = (size_t)(b*4096 + n0) * 256;
    us8 v[8];
    #pragma unroll
    for (int j=0;j<8;j++)
      v[j] = *(const us8*)&phi_q[gbase + (size_t)(j*256 + t)*8];
    #pragma unroll
    for (int j=0;j<8;j++) {
      const int g = (j*256 + t) * 8;
      *(us8*)&A_lds[g >> 8][g & 255] = v[j];
    }
  }
  __syncthreads();

  f32x4 acc[4][4];
  #pragma unroll
  for (int i=0;i<4;i++)
    #pragma unroll
    for (int j=0;j<4;j++) acc[i][j] = (f32x4){0.f,0.f,0.f,0.f};

  const u16* kb = KV_nT + (size_t)(b*256 + we*64 + i16)*256 + q*8;
  short8 Bfr[3][4];
  #pragma unroll
  for (int ei=0;ei<4;ei++) Bfr[0][ei] = *(const short8*)&kb[ei*4096];
  #pragma unroll
  for (int ei=0;ei<4;ei++) Bfr[1][ei] = *(const short8*)&kb[ei*4096 + 32];

  #pragma unroll
  for (int it=0; it<8; it++){
    if (it < 6) {
      #pragma unroll
      for (int ei=0;ei<4;ei++)
        Bfr[(it+2)%3][ei] = *(const short8*)&kb[ei*4096 + (it+2)*32];
    }
    short8 af[4];
    #pragma unroll
    for (int mi=0;mi<4;mi++)
      af[mi] = *(const short8*)&A_lds[mi*16 + i16][it*32 + q*8];
    #pragma unroll
    for (int mi=0;mi<4;mi++)
      #pragma unroll
      for (int ei=0;ei<4;ei++)
        acc[mi][ei] = __builtin_amdgcn_mfma_f32_16x16x32_bf16(af[mi], Bfr[it%3][ei], acc[mi][ei],0,0,0);
  }

  #pragma unroll
  for (int mi=0;mi<4;mi++){
    #pragma unroll
    for (int r=0;r<4;r++){
      const int nl = mi*16 + q*4 + r;
      const float rs = rs_lds[nl];
      const float gate = sigmoidf_(rs) / (rs + EPS_);
      #pragma unroll
      for (int ei=0;ei<4;ei++)
        outp[((size_t)(b*4096 + n0 + nl))*256 + we*64 + ei*16 + i16] = gate*acc[mi][ei][r];
    }
  }
}

extern "C" void kernel_launch(void* const* d_in, const int* in_sizes, int n_in,
                              void* d_out, int out_size, void* d_ws, size_t ws_size,
                              hipStream_t stream) {
  const float* Q  = (const float*)d_in[0];
  const float* K  = (const float*)d_in[1];
  const float* V  = (const float*)d_in[2];
  const float* Wq = (const float*)d_in[3];
  const float* bq = (const float*)d_in[4];
  const float* Wk = (const float*)d_in[5];
  const float* bk = (const float*)d_in[6];
  float* out = (float*)d_out;

  u16* phi_q  = (u16*)d_ws;                 // 16,777,216 bf16 [b][n][d]
  u16* phi_kT = phi_q + 16777216;           // 16,777,216 bf16 TILED [b][nchunk][d][n64]
  u16* WqT    = phi_kT + 16777216;          // 65,536
  u16* WkT    = WqT + 65536;                // 65,536
  float* colsum = (float*)(WkT + 65536);    // 4096
  float* denom  = colsum + 4096;            // 4096
  float* rowsum = denom + 4096;             // 65,536
  u16* partsT = (u16*)(rowsum + 65536);     // 16*16*65536 bf16 (33.5 MB) [nc][b][e][d]
  u16* KV_nT  = partsT + 16777216;          // 1,048,576 bf16 [b][e][d]

  hipMemsetAsync(colsum, 0, (4096 + 4096 + 65536) * sizeof(float), stream);

  prep_w<<<dim3(512), 256, 0, stream>>>(Wq, Wk, WqT, WkT);
  phi_both<<<dim3(1024, 1, 2), 256, 0, stream>>>(Q, K, WqT, WkT, bq, bk,
                                                 phi_q, phi_kT, rowsum, colsum);
  kv_kernel<<<dim3(4, 16, 16), 256, 0, stream>>>(phi_kT, V, colsum, partsT, denom);
  kv_norm<<<dim3(64, 16), 256, 0, stream>>>(partsT, denom, KV_nT);
  out_gemm<<<dim3(64, 16), 256, 0, stream>>>(phi_q, KV_nT, rowsum, out);
}

// Round 3
// 286.951 us; speedup vs baseline: 1.1445x; 1.0470x over previous
//
#include <hip/hip_runtime.h>
#include <cstddef>

#define EPS_ 1e-6f

typedef unsigned short u16;
typedef __attribute__((ext_vector_type(8))) short short8;      // bf16x8 MFMA frag
typedef __attribute__((ext_vector_type(8))) unsigned short us8;
typedef __attribute__((ext_vector_type(4))) unsigned short us4;
typedef __attribute__((ext_vector_type(4))) float f32x4;

__device__ __forceinline__ float sigmoidf_(float x){ return 1.0f/(1.0f+__expf(-x)); }
// fast sigmoid: v_rcp_f32 (~1 ulp) instead of IEEE divide; result goes to bf16.
__device__ __forceinline__ float sigmoidf_fast(float x){
  return __builtin_amdgcn_rcpf(1.0f+__expf(-x));
}
__device__ __forceinline__ u16 f2bf(float x){
  union { __bf16 b; u16 u; } c; c.b = (__bf16)x; return c.u;   // RNE, hw cvt if avail
}
__device__ __forceinline__ float bf2f(u16 u){
  union { unsigned i; float f; } c; c.i = ((unsigned)u) << 16; return c.f;
}
__device__ __forceinline__ us4 cvt4(float4 v){
  us4 h; h[0]=f2bf(v.x); h[1]=f2bf(v.y); h[2]=f2bf(v.z); h[3]=f2bf(v.w); return h;
}

// ---------------------------------------------------------------------------
// prep_w v2: emit W in MFMA B-FRAGMENT order so phi's B-loads are 1-segment.
// WTf[((eb*8+it)*64 + lane)*8 + j] = bf16( W[d][e] ),
//   e = eb*16 + (lane&15), d = it*32 + (lane>>4)*8 + j.
// Consumer (wave wf, frag fi, step it, lane l): base = wf*16384 + l*8,
// offset = fi*4096 + it*512  -> one contiguous 1KB wave load.
// ---------------------------------------------------------------------------
__global__ __launch_bounds__(256) void prep_w(const float* __restrict__ Wq,
                                              const float* __restrict__ Wk,
                                              u16* __restrict__ WqT,
                                              u16* __restrict__ WkT){
  const int m  = blockIdx.x >> 4;          // 0 = q, 1 = k
  const int eb = blockIdx.x & 15;
  const float* W = m ? Wk : Wq;
  u16* WTf = m ? WkT : WqT;
  const int t = threadIdx.x;
  #pragma unroll
  for (int rep = 0; rep < 2; rep++) {
    const int lin  = rep*256 + t;
    const int it   = lin >> 6;
    const int lane = lin & 63;
    const int q    = lane >> 4;
    const int i16  = lane & 15;
    us8 o;
    #pragma unroll
    for (int j = 0; j < 8; j++)
      o[j] = f2bf(W[(it*32 + q*8 + j)*256 + eb*16 + i16]);
    *(us8*)&WTf[(size_t)((eb*8 + it)*512 + lane*8)] = o;
  }
}

// ---------------------------------------------------------------------------
// phi_both v6: identical to v5 except the W stream now reads the fragment-
// ordered WTf layout: each B-load is one contiguous 1KB wave transaction
// (was 16 x 64B segments across 512B-strided rows -> 512 L1/L2 transactions
// per wave per tile on the B stream alone).
// ---------------------------------------------------------------------------
__global__ __launch_bounds__(256, 3) void phi_both(
    const float* __restrict__ Q, const float* __restrict__ K,
    const u16* __restrict__ WqT, const u16* __restrict__ WkT,
    const float* __restrict__ bq, const float* __restrict__ bk,
    u16* __restrict__ phi_q, u16* __restrict__ phi_kT,
    float* __restrict__ rowsum, float* __restrict__ colsum)
{
  __shared__ union {
    u16 A[64][264];     // [row][k] staging, 33792 B (row 528 B = 16B mult)
    u16 S[64][264];     // !trans epilogue [row][f]
    u16 T2[128][136];   // trans epilogue half-pass [f&127][n], 34816 B
  } sh;

  const int t = threadIdx.x;
  const int l = t & 63;
  const int wf = t >> 6;          // f-quarter
  const int i16 = l & 15, q = l >> 4;
  const int row0 = blockIdx.x * 64;
  const bool trans = (blockIdx.z != 0);

  const float* X    = trans ? K   : Q;
  const u16*  WT    = trans ? WkT : WqT;
  const float* bias = trans ? bk  : bq;

  // ---- stage X tile (64x256 f32 -> bf16 LDS), 2 batches of 8 float4 ----
  {
    const int r0 = t >> 4;        // 0..15
    const int c0 = t & 15;        // float4 col
    #pragma unroll
    for (int half = 0; half < 2; half++) {
      float4 v[8];
      #pragma unroll
      for (int p = 0; p < 8; p++) {
        const int row = r0 + 16*(half*2 + (p >> 2));
        const int k4  = c0 + 16*(p & 3);
        v[p] = *(const float4*)&X[(size_t)(row0 + row)*256 + k4*4];
      }
      #pragma unroll
      for (int p = 0; p < 8; p++) {
        const int row = r0 + 16*(half*2 + (p >> 2));
        const int k4  = c0 + 16*(p & 3);
        *(us4*)&sh.A[row][k4*4] = cvt4(v[p]);
      }
    }
  }
  __syncthreads();

  // ---- K loop: 8 steps, no barriers, 2-deep W prefetch, coalesced B ----
  f32x4 acc[4][4];
  #pragma unroll
  for (int i=0;i<4;i++)
    #pragma unroll
    for (int j=0;j<4;j++) acc[i][j] = (f32x4){0.f,0.f,0.f,0.f};

  const u16* wbf = WT + (size_t)wf*16384 + (size_t)l*8;
  short8 Bfr[3][4];
  #pragma unroll
  for (int fi=0;fi<4;fi++) Bfr[0][fi] = *(const short8*)&wbf[fi*4096];
  #pragma unroll
  for (int fi=0;fi<4;fi++) Bfr[1][fi] = *(const short8*)&wbf[fi*4096 + 512];

  #pragma unroll
  for (int it = 0; it < 8; it++) {
    if (it < 6) {
      #pragma unroll
      for (int fi=0;fi<4;fi++)
        Bfr[(it+2)%3][fi] = *(const short8*)&wbf[fi*4096 + (it+2)*512];
    }
    short8 af[4];
    #pragma unroll
    for (int mi=0;mi<4;mi++)
      af[mi] = *(const short8*)&sh.A[mi*16 + i16][it*32 + q*8];
    #pragma unroll
    for (int mi=0;mi<4;mi++)
      #pragma unroll
      for (int fi=0;fi<4;fi++)
        acc[mi][fi] = __builtin_amdgcn_mfma_f32_16x16x32_bf16(af[mi], Bfr[it%3][fi], acc[mi][fi], 0,0,0);
  }

  float bv[4];
  #pragma unroll
  for (int fi=0;fi<4;fi++) bv[fi] = bias[wf*64 + fi*16 + i16];

  __syncthreads();   // A reads done; LDS reusable

  if (!trans) {
    #pragma unroll
    for (int mi=0;mi<4;mi++) {
      float rsub[4] = {0.f,0.f,0.f,0.f};
      #pragma unroll
      for (int fi=0;fi<4;fi++) {
        #pragma unroll
        for (int r=0;r<4;r++) {
          float ph = sigmoidf_fast(acc[mi][fi][r] + bv[fi]);
          rsub[r] += ph;
          sh.S[mi*16 + q*4 + r][wf*64 + fi*16 + i16] = f2bf(ph);
        }
      }
      #pragma unroll
      for (int r=0;r<4;r++) {
        float s = rsub[r];
        s += __shfl_xor(s,1); s += __shfl_xor(s,2); s += __shfl_xor(s,4); s += __shfl_xor(s,8);
        if (i16 == 0) atomicAdd(&rowsum[row0 + mi*16 + q*4 + r], s);
      }
    }
    __syncthreads();
    const size_t gbase = (size_t)row0 * 256;
    #pragma unroll
    for (int j=0;j<8;j++) {
      const int g = (j*256 + t) * 8;       // u16 index in 16384
      *(us8*)&phi_q[gbase + g] = *(const us8*)&sh.S[g >> 8][g & 255];
    }
  } else {
    const int b      = row0 >> 12;
    const int nchunk = (row0 & 4095) >> 6;
    #pragma unroll
    for (int h = 0; h < 2; h++) {
      if ((wf >> 1) == h) {
        #pragma unroll
        for (int fi=0;fi<4;fi++) {
          float cp = 0.f;
          #pragma unroll
          for (int mi=0;mi<4;mi++) {
            #pragma unroll
            for (int r=0;r<4;r++) {
              float ph = sigmoidf_fast(acc[mi][fi][r] + bv[fi]);
              cp += ph;
              sh.T2[(wf*64 + fi*16 + i16) & 127][mi*16 + q*4 + r] = f2bf(ph);
            }
          }
          cp += __shfl_xor(cp,16); cp += __shfl_xor(cp,32);   // reduce over q
          if (l < 16) atomicAdd(&colsum[b*256 + wf*64 + fi*16 + l], cp);
        }
      }
      __syncthreads();
      // contiguous 16 KB tile store: [f 128][n 64] u16
      const size_t gb = ((size_t)(b*64 + nchunk)*256 + h*128) * 64;
      #pragma unroll
      for (int j=0;j<4;j++) {
        const int g = (j*256 + t) * 8;     // u16 index in 8192
        *(us8*)&phi_kT[gb + g] = *(const us8*)&sh.T2[g >> 6][g & 63];
      }
      __syncthreads();
    }
  }
}

// ---------------------------------------------------------------------------
// KV partials: grid (e0/64, nc 0..15, b). Block: d=256 x e=64, 4 chunks of 64 n.
// phi_kT is tiled [b][nchunk][d][n64] -> perfectly contiguous 32 KB chunk reads.
// E[n,e] = exp(phi_k*inv_cs*V); denom f32 atomics.
// v2: partsT now stored in a fragment-flat layout (contiguous 512B wave
// stores instead of 8B scatters at 512B stride):
//   partsT[(nc*16+b)*65536 + e0blk*16384 + ((w*16+mi*4+ei)*64 + l)*4 + r]
//   where e = e0blk*64 + ei*16 + (l&15), d = w*64 + mi*16 + (l>>4)*4 + r.
// kv_norm inverts this mapping.
// ---------------------------------------------------------------------------
__global__ __launch_bounds__(256) void kv_kernel(const u16* __restrict__ phi_kT,
    const float* __restrict__ V, const float* __restrict__ colsum,
    u16* __restrict__ partsT, float* __restrict__ denom)
{
  __shared__ u16 phiT_lds[256][72];   // [d][n 64]
  __shared__ u16 E_lds[64][72];       // [e][n 64]

  const int t = threadIdx.x;
  const int l = t & 63;
  const int w = t >> 6;
  const int e0 = blockIdx.x * 64;
  const int nc = blockIdx.y;
  const int b  = blockIdx.z;
  const int i16 = l & 15, q = l >> 4;

  const int sd = t >> 3;          // staging d-base (0..31)
  const int sn = (t & 7) * 8;     // staging n-offset

  const size_t cbase = (size_t)(b*64 + nc*4) * 256 * 64;   // u16 idx of chunk 0

  us8  rA[8];
  float rV[16];
  #pragma unroll
  for (int p=0;p<8;p++)
    rA[p] = *(const us8*)&phi_kT[cbase + (size_t)(sd + 32*p)*64 + sn];
  #pragma unroll
  for (int j=0;j<16;j++)
    rV[j] = V[(size_t)(b*4096 + nc*256 + w*16 + j)*256 + e0 + l];

  const float inv_cs = 1.0f / (colsum[b*256 + e0 + l] + EPS_);
  float dsum = 0.f;

  f32x4 acc[4][4];
  #pragma unroll
  for (int i=0;i<4;i++)
    #pragma unroll
    for (int j=0;j<4;j++) acc[i][j] = (f32x4){0.f,0.f,0.f,0.f};

  for (int c = 0; c < 4; c++) {
    #pragma unroll
    for (int p=0;p<8;p++) *(us8*)&phiT_lds[sd + 32*p][sn] = rA[p];
    __syncthreads();
    if (c < 3) {
      const size_t nb = cbase + (size_t)(c+1)*16384;
      #pragma unroll
      for (int p=0;p<8;p++)
        rA[p] = *(const us8*)&phi_kT[nb + (size_t)(sd + 32*p)*64 + sn];
    }
    us8 pv0 = *(const us8*)&phiT_lds[e0 + l][w*16];
    us8 pv1 = *(const us8*)&phiT_lds[e0 + l][w*16 + 8];
    us8 ev0, ev1;
    #pragma unroll
    for (int j=0;j<8;j++) {
      float ef = __expf(bf2f(pv0[j]) * inv_cs * rV[j]);
      dsum += ef; ev0[j] = f2bf(ef);
    }
    #pragma unroll
    for (int j=0;j<8;j++) {
      float ef = __expf(bf2f(pv1[j]) * inv_cs * rV[8+j]);
      dsum += ef; ev1[j] = f2bf(ef);
    }
    *(us8*)&E_lds[l][w*16]     = ev0;
    *(us8*)&E_lds[l][w*16 + 8] = ev1;
    if (c < 3) {
      #pragma unroll
      for (int j=0;j<16;j++)
        rV[j] = V[(size_t)(b*4096 + nc*256 + (c+1)*64 + w*16 + j)*256 + e0 + l];
    }
    __syncthreads();
    #pragma unroll
    for (int kk=0;kk<2;kk++){
      const int ko = kk*32 + q*8;
      short8 af[4], bfr[4];
      #pragma unroll
      for (int mi=0;mi<4;mi++) af[mi]  = *(const short8*)&phiT_lds[w*64 + mi*16 + i16][ko];
      #pragma unroll
      for (int ei=0;ei<4;ei++) bfr[ei] = *(const short8*)&E_lds[ei*16 + i16][ko];
      #pragma unroll
      for (int mi=0;mi<4;mi++)
        #pragma unroll
        for (int ei=0;ei<4;ei++)
          acc[mi][ei] = __builtin_amdgcn_mfma_f32_16x16x32_bf16(af[mi], bfr[ei], acc[mi][ei],0,0,0);
    }
    __syncthreads();
  }

  atomicAdd(&denom[b*256 + e0 + l], dsum);

  // fragment-flat partial store: contiguous 512B per wave-store
  u16* slice = partsT + (size_t)(nc*16 + b) * 65536 + (size_t)blockIdx.x * 16384;
  #pragma unroll
  for (int mi=0;mi<4;mi++)
    #pragma unroll
    for (int ei=0;ei<4;ei++) {
      us4 o;
      #pragma unroll
      for (int r=0;r<4;r++) o[r] = f2bf(acc[mi][ei][r]);
      *(us4*)&slice[(size_t)(((w*16 + mi*4 + ei)*64 + l)*4)] = o;
    }
}

// ---------------------------------------------------------------------------
// kv_norm v2: reduce fragment-flat partsT over nc, divide by denom, and emit
// KV_n in the MFMA B-FRAGMENT order out_gemm consumes:
//   KVf[b*65536 + (eb*8+it)*512 + lane*8 + j],
//   e = eb*16 + (lane&15), d = it*32 + (lane>>4)*8 + j.
// ---------------------------------------------------------------------------
__global__ __launch_bounds__(256) void kv_norm(const u16* __restrict__ partsT,
    const float* __restrict__ denom, u16* __restrict__ KV_nT)
{
  const int t = threadIdx.x;
  const int b = blockIdx.y;
  const int s4 = blockIdx.x*256 + t;        // us4 slot, 0..16383
  const int e0b = s4 >> 12;
  const int rem = s4 & 4095;
  const int comb = rem >> 6;                // w*16 + mi*4 + ei
  const int l = rem & 63;
  const int w  = comb >> 4;
  const int mi = (comb >> 2) & 3;
  const int ei = comb & 3;
  const int e  = e0b*64 + ei*16 + (l & 15);
  const int d0 = w*64 + mi*16 + (l >> 4)*4;

  const float dn = denom[b*256 + e];
  float s0=0.f,s1=0.f,s2=0.f,s3=0.f;
  #pragma unroll 4
  for (int nc=0;nc<16;nc++){
    us4 v = *(const us4*)&partsT[(size_t)(nc*16 + b)*65536 + (size_t)s4*4];
    s0+=bf2f(v[0]); s1+=bf2f(v[1]); s2+=bf2f(v[2]); s3+=bf2f(v[3]);
  }
  us4 o; o[0]=f2bf(s0/dn); o[1]=f2bf(s1/dn); o[2]=f2bf(s2/dn); o[3]=f2bf(s3/dn);

  const int eb  = e >> 4;
  const int i16 = e & 15;
  const int it  = d0 >> 5;
  const int qo  = (d0 >> 3) & 3;
  const int j0  = d0 & 4;
  *(us4*)&KV_nT[(size_t)b*65536 + (size_t)((eb*8 + it)*512 + (qo*16 + i16)*8 + j0)] = o;
}

// ---------------------------------------------------------------------------
// out[b,n,e] = sigmoid(rs)/(rs+eps) * sum_d phi_q[n,d] * KV_n[d,e]
// v4: B stream reads fragment-ordered KVf (1KB contiguous wave loads),
// otherwise identical to v3.
// ---------------------------------------------------------------------------
__global__ __launch_bounds__(256, 3) void out_gemm(const u16* __restrict__ phi_q,
    const u16* __restrict__ KV_nT, const float* __restrict__ rowsum,
    float* __restrict__ outp)
{
  __shared__ u16 A_lds[64][264];
  __shared__ float rs_lds[64];

  const int t = threadIdx.x;
  const int l = t & 63;
  const int we = t >> 6;
  const int i16 = l & 15, q = l >> 4;
  const int n0 = blockIdx.x * 64;
  const int b  = blockIdx.y;

  if (t < 64) rs_lds[t] = rowsum[b*4096 + n0 + t];

  {
    const size_t gbase = (size_t)(b*4096 + n0) * 256;
    us8 v[8];
    #pragma unroll
    for (int j=0;j<8;j++)
      v[j] = *(const us8*)&phi_q[gbase + (size_t)(j*256 + t)*8];
    #pragma unroll
    for (int j=0;j<8;j++) {
      const int g = (j*256 + t) * 8;
      *(us8*)&A_lds[g >> 8][g & 255] = v[j];
    }
  }
  __syncthreads();

  f32x4 acc[4][4];
  #pragma unroll
  for (int i=0;i<4;i++)
    #pragma unroll
    for (int j=0;j<4;j++) acc[i][j] = (f32x4){0.f,0.f,0.f,0.f};

  const u16* kbf = KV_nT + (size_t)b*65536 + (size_t)we*16384 + (size_t)l*8;
  short8 Bfr[3][4];
  #pragma unroll
  for (int ei=0;ei<4;ei++) Bfr[0][ei] = *(const short8*)&kbf[ei*4096];
  #pragma unroll
  for (int ei=0;ei<4;ei++) Bfr[1][ei] = *(const short8*)&kbf[ei*4096 + 512];

  #pragma unroll
  for (int it=0; it<8; it++){
    if (it < 6) {
      #pragma unroll
      for (int ei=0;ei<4;ei++)
        Bfr[(it+2)%3][ei] = *(const short8*)&kbf[ei*4096 + (it+2)*512];
    }
    short8 af[4];
    #pragma unroll
    for (int mi=0;mi<4;mi++)
      af[mi] = *(const short8*)&A_lds[mi*16 + i16][it*32 + q*8];
    #pragma unroll
    for (int mi=0;mi<4;mi++)
      #pragma unroll
      for (int ei=0;ei<4;ei++)
        acc[mi][ei] = __builtin_amdgcn_mfma_f32_16x16x32_bf16(af[mi], Bfr[it%3][ei], acc[mi][ei],0,0,0);
  }

  #pragma unroll
  for (int mi=0;mi<4;mi++){
    #pragma unroll
    for (int r=0;r<4;r++){
      const int nl = mi*16 + q*4 + r;
      const float rs = rs_lds[nl];
      const float gate = sigmoidf_(rs) / (rs + EPS_);
      #pragma unroll
      for (int ei=0;ei<4;ei++)
        outp[((size_t)(b*4096 + n0 + nl))*256 + we*64 + ei*16 + i16] = gate*acc[mi][ei][r];
    }
  }
}

extern "C" void kernel_launch(void* const* d_in, const int* in_sizes, int n_in,
                              void* d_out, int out_size, void* d_ws, size_t ws_size,
                              hipStream_t stream) {
  const float* Q  = (const float*)d_in[0];
  const float* K  = (const float*)d_in[1];
  const float* V  = (const float*)d_in[2];
  const float* Wq = (const float*)d_in[3];
  const float* bq = (const float*)d_in[4];
  const float* Wk = (const float*)d_in[5];
  const float* bk = (const float*)d_in[6];
  float* out = (float*)d_out;

  u16* phi_q  = (u16*)d_ws;                 // 16,777,216 bf16 [b][n][d]
  u16* phi_kT = phi_q + 16777216;           // 16,777,216 bf16 TILED [b][nchunk][d][n64]
  u16* WqT    = phi_kT + 16777216;          // 65,536 (fragment order)
  u16* WkT    = WqT + 65536;                // 65,536 (fragment order)
  float* colsum = (float*)(WkT + 65536);    // 4096
  float* denom  = colsum + 4096;            // 4096
  float* rowsum = denom + 4096;             // 65,536
  u16* partsT = (u16*)(rowsum + 65536);     // 16*16*65536 bf16 (fragment-flat)
  u16* KV_nT  = partsT + 16777216;          // 1,048,576 bf16 (fragment order)

  hipMemsetAsync(colsum, 0, (4096 + 4096 + 65536) * sizeof(float), stream);

  prep_w<<<dim3(32), 256, 0, stream>>>(Wq, Wk, WqT, WkT);
  phi_both<<<dim3(1024, 1, 2), 256, 0, stream>>>(Q, K, WqT, WkT, bq, bk,
                                                 phi_q, phi_kT, rowsum, colsum);
  kv_kernel<<<dim3(4, 16, 16), 256, 0, stream>>>(phi_kT, V, colsum, partsT, denom);
  kv_norm<<<dim3(64, 16), 256, 0, stream>>>(partsT, denom, KV_nT);
  out_gemm<<<dim3(64, 16), 256, 0, stream>>>(phi_q, KV_nT, rowsum, out);
}

// Round 4
// 281.381 us; speedup vs baseline: 1.1671x; 1.0198x over previous
//
#include <hip/hip_runtime.h>
#include <cstddef>

#define EPS_ 1e-6f

typedef unsigned short u16;
typedef __attribute__((ext_vector_type(8))) short short8;      // bf16x8 MFMA frag
typedef __attribute__((ext_vector_type(8))) unsigned short us8;
typedef __attribute__((ext_vector_type(4))) unsigned short us4;
typedef __attribute__((ext_vector_type(4))) float f32x4;

__device__ __forceinline__ float sigmoidf_(float x){ return 1.0f/(1.0f+__expf(-x)); }
// fast sigmoid: v_rcp_f32 (~1 ulp) instead of IEEE divide; result goes to bf16.
__device__ __forceinline__ float sigmoidf_fast(float x){
  return __builtin_amdgcn_rcpf(1.0f+__expf(-x));
}
__device__ __forceinline__ u16 f2bf(float x){
  union { __bf16 b; u16 u; } c; c.b = (__bf16)x; return c.u;   // RNE, hw cvt if avail
}
__device__ __forceinline__ float bf2f(u16 u){
  union { unsigned i; float f; } c; c.i = ((unsigned)u) << 16; return c.f;
}
__device__ __forceinline__ us4 cvt4(float4 v){
  us4 h; h[0]=f2bf(v.x); h[1]=f2bf(v.y); h[2]=f2bf(v.z); h[3]=f2bf(v.w); return h;
}

// ---------------------------------------------------------------------------
// prep_w: emit W in MFMA B-FRAGMENT order so phi/out GEMM B-loads are
// single-segment 1KB wave transactions.
// WTf[((eb*8+it)*64 + lane)*8 + j] = bf16( W[d][e] ),
//   e = eb*16 + (lane&15), d = it*32 + (lane>>4)*8 + j.
// ---------------------------------------------------------------------------
__global__ __launch_bounds__(256) void prep_w(const float* __restrict__ Wq,
                                              const float* __restrict__ Wk,
                                              u16* __restrict__ WqT,
                                              u16* __restrict__ WkT){
  const int m  = blockIdx.x >> 4;          // 0 = q, 1 = k
  const int eb = blockIdx.x & 15;
  const float* W = m ? Wk : Wq;
  u16* WTf = m ? WkT : WqT;
  const int t = threadIdx.x;
  #pragma unroll
  for (int rep = 0; rep < 2; rep++) {
    const int lin  = rep*256 + t;
    const int it   = lin >> 6;
    const int lane = lin & 63;
    const int q    = lane >> 4;
    const int i16  = lane & 15;
    us8 o;
    #pragma unroll
    for (int j = 0; j < 8; j++)
      o[j] = f2bf(W[(it*32 + q*8 + j)*256 + eb*16 + i16]);
    *(us8*)&WTf[(size_t)((eb*8 + it)*512 + lane*8)] = o;
  }
}

// ---------------------------------------------------------------------------
// phi_k (was phi_both trans-branch): phi_kT = sigmoid(K@Wk+bk)^T tiled
// [b][nchunk][f][n64] + colsum atomics. The q-side is now fused into out_fused
// (deletes phi_q 32MB write + 32MB read + rowsum atomics pass).
// ---------------------------------------------------------------------------
__global__ __launch_bounds__(256, 3) void phi_k(
    const float* __restrict__ K, const u16* __restrict__ WkT,
    const float* __restrict__ bk,
    u16* __restrict__ phi_kT, float* __restrict__ colsum)
{
  __shared__ union {
    u16 A[64][264];     // [row][k] staging, 33792 B
    u16 T2[128][136];   // trans epilogue half-pass [f&127][n], 34816 B
  } sh;

  const int t = threadIdx.x;
  const int l = t & 63;
  const int wf = t >> 6;          // f-quarter
  const int i16 = l & 15, q = l >> 4;
  const int row0 = blockIdx.x * 64;

  // ---- stage K tile (64x256 f32 -> bf16 LDS), 2 batches of 8 float4 ----
  {
    const int r0 = t >> 4;
    const int c0 = t & 15;
    #pragma unroll
    for (int half = 0; half < 2; half++) {
      float4 v[8];
      #pragma unroll
      for (int p = 0; p < 8; p++) {
        const int row = r0 + 16*(half*2 + (p >> 2));
        const int k4  = c0 + 16*(p & 3);
        v[p] = *(const float4*)&K[(size_t)(row0 + row)*256 + k4*4];
      }
      #pragma unroll
      for (int p = 0; p < 8; p++) {
        const int row = r0 + 16*(half*2 + (p >> 2));
        const int k4  = c0 + 16*(p & 3);
        *(us4*)&sh.A[row][k4*4] = cvt4(v[p]);
      }
    }
  }
  __syncthreads();

  // ---- K loop: 8 steps, 2-deep W prefetch, fragment-order B ----
  f32x4 acc[4][4];
  #pragma unroll
  for (int i=0;i<4;i++)
    #pragma unroll
    for (int j=0;j<4;j++) acc[i][j] = (f32x4){0.f,0.f,0.f,0.f};

  const u16* wbf = WkT + (size_t)wf*16384 + (size_t)l*8;
  short8 Bfr[3][4];
  #pragma unroll
  for (int fi=0;fi<4;fi++) Bfr[0][fi] = *(const short8*)&wbf[fi*4096];
  #pragma unroll
  for (int fi=0;fi<4;fi++) Bfr[1][fi] = *(const short8*)&wbf[fi*4096 + 512];

  #pragma unroll
  for (int it = 0; it < 8; it++) {
    if (it < 6) {
      #pragma unroll
      for (int fi=0;fi<4;fi++)
        Bfr[(it+2)%3][fi] = *(const short8*)&wbf[fi*4096 + (it+2)*512];
    }
    short8 af[4];
    #pragma unroll
    for (int mi=0;mi<4;mi++)
      af[mi] = *(const short8*)&sh.A[mi*16 + i16][it*32 + q*8];
    #pragma unroll
    for (int mi=0;mi<4;mi++)
      #pragma unroll
      for (int fi=0;fi<4;fi++)
        acc[mi][fi] = __builtin_amdgcn_mfma_f32_16x16x32_bf16(af[mi], Bfr[it%3][fi], acc[mi][fi], 0,0,0);
  }

  float bv[4];
  #pragma unroll
  for (int fi=0;fi<4;fi++) bv[fi] = bk[wf*64 + fi*16 + i16];

  __syncthreads();   // A reads done; LDS reusable

  const int b      = row0 >> 12;
  const int nchunk = (row0 & 4095) >> 6;
  #pragma unroll
  for (int h = 0; h < 2; h++) {
    if ((wf >> 1) == h) {
      #pragma unroll
      for (int fi=0;fi<4;fi++) {
        float cp = 0.f;
        #pragma unroll
        for (int mi=0;mi<4;mi++) {
          #pragma unroll
          for (int r=0;r<4;r++) {
            float ph = sigmoidf_fast(acc[mi][fi][r] + bv[fi]);
            cp += ph;
            sh.T2[(wf*64 + fi*16 + i16) & 127][mi*16 + q*4 + r] = f2bf(ph);
          }
        }
        cp += __shfl_xor(cp,16); cp += __shfl_xor(cp,32);   // reduce over q
        if (l < 16) atomicAdd(&colsum[b*256 + wf*64 + fi*16 + l], cp);
      }
    }
    __syncthreads();
    // contiguous 16 KB tile store: [f 128][n 64] u16
    const size_t gb = ((size_t)(b*64 + nchunk)*256 + h*128) * 64;
    #pragma unroll
    for (int j=0;j<4;j++) {
      const int g = (j*256 + t) * 8;     // u16 index in 8192
      *(us8*)&phi_kT[gb + g] = *(const us8*)&sh.T2[g >> 6][g & 63];
    }
    __syncthreads();
  }
}

// ---------------------------------------------------------------------------
// KV partials: grid (e0/64, nc 0..15, b). Block: d=256 x e=64, 4 chunks of 64 n.
// phi_kT tiled -> contiguous 32 KB chunk reads. E = exp(phi_k*inv_cs*V).
// partsT fragment-flat (contiguous 512B wave stores). denom f32 atomics.
// ---------------------------------------------------------------------------
__global__ __launch_bounds__(256) void kv_kernel(const u16* __restrict__ phi_kT,
    const float* __restrict__ V, const float* __restrict__ colsum,
    u16* __restrict__ partsT, float* __restrict__ denom)
{
  __shared__ u16 phiT_lds[256][72];   // [d][n 64]
  __shared__ u16 E_lds[64][72];       // [e][n 64]

  const int t = threadIdx.x;
  const int l = t & 63;
  const int w = t >> 6;
  const int e0 = blockIdx.x * 64;
  const int nc = blockIdx.y;
  const int b  = blockIdx.z;
  const int i16 = l & 15, q = l >> 4;

  const int sd = t >> 3;          // staging d-base (0..31)
  const int sn = (t & 7) * 8;     // staging n-offset

  const size_t cbase = (size_t)(b*64 + nc*4) * 256 * 64;   // u16 idx of chunk 0

  us8  rA[8];
  float rV[16];
  #pragma unroll
  for (int p=0;p<8;p++)
    rA[p] = *(const us8*)&phi_kT[cbase + (size_t)(sd + 32*p)*64 + sn];
  #pragma unroll
  for (int j=0;j<16;j++)
    rV[j] = V[(size_t)(b*4096 + nc*256 + w*16 + j)*256 + e0 + l];

  const float inv_cs = 1.0f / (colsum[b*256 + e0 + l] + EPS_);
  float dsum = 0.f;

  f32x4 acc[4][4];
  #pragma unroll
  for (int i=0;i<4;i++)
    #pragma unroll
    for (int j=0;j<4;j++) acc[i][j] = (f32x4){0.f,0.f,0.f,0.f};

  for (int c = 0; c < 4; c++) {
    #pragma unroll
    for (int p=0;p<8;p++) *(us8*)&phiT_lds[sd + 32*p][sn] = rA[p];
    __syncthreads();
    if (c < 3) {
      const size_t nb = cbase + (size_t)(c+1)*16384;
      #pragma unroll
      for (int p=0;p<8;p++)
        rA[p] = *(const us8*)&phi_kT[nb + (size_t)(sd + 32*p)*64 + sn];
    }
    us8 pv0 = *(const us8*)&phiT_lds[e0 + l][w*16];
    us8 pv1 = *(const us8*)&phiT_lds[e0 + l][w*16 + 8];
    us8 ev0, ev1;
    #pragma unroll
    for (int j=0;j<8;j++) {
      float ef = __expf(bf2f(pv0[j]) * inv_cs * rV[j]);
      dsum += ef; ev0[j] = f2bf(ef);
    }
    #pragma unroll
    for (int j=0;j<8;j++) {
      float ef = __expf(bf2f(pv1[j]) * inv_cs * rV[8+j]);
      dsum += ef; ev1[j] = f2bf(ef);
    }
    *(us8*)&E_lds[l][w*16]     = ev0;
    *(us8*)&E_lds[l][w*16 + 8] = ev1;
    if (c < 3) {
      #pragma unroll
      for (int j=0;j<16;j++)
        rV[j] = V[(size_t)(b*4096 + nc*256 + (c+1)*64 + w*16 + j)*256 + e0 + l];
    }
    __syncthreads();
    #pragma unroll
    for (int kk=0;kk<2;kk++){
      const int ko = kk*32 + q*8;
      short8 af[4], bfr[4];
      #pragma unroll
      for (int mi=0;mi<4;mi++) af[mi]  = *(const short8*)&phiT_lds[w*64 + mi*16 + i16][ko];
      #pragma unroll
      for (int ei=0;ei<4;ei++) bfr[ei] = *(const short8*)&E_lds[ei*16 + i16][ko];
      #pragma unroll
      for (int mi=0;mi<4;mi++)
        #pragma unroll
        for (int ei=0;ei<4;ei++)
          acc[mi][ei] = __builtin_amdgcn_mfma_f32_16x16x32_bf16(af[mi], bfr[ei], acc[mi][ei],0,0,0);
    }
    __syncthreads();
  }

  atomicAdd(&denom[b*256 + e0 + l], dsum);

  // fragment-flat partial store: contiguous 512B per wave-store
  u16* slice = partsT + (size_t)(nc*16 + b) * 65536 + (size_t)blockIdx.x * 16384;
  #pragma unroll
  for (int mi=0;mi<4;mi++)
    #pragma unroll
    for (int ei=0;ei<4;ei++) {
      us4 o;
      #pragma unroll
      for (int r=0;r<4;r++) o[r] = f2bf(acc[mi][ei][r]);
      *(us4*)&slice[(size_t)(((w*16 + mi*4 + ei)*64 + l)*4)] = o;
    }
}

// ---------------------------------------------------------------------------
// kv_norm: reduce fragment-flat partsT over nc, divide by denom, emit KV_n in
// MFMA B-FRAGMENT order:
//   KVf[b*65536 + (eb*8+it)*512 + lane*8 + j],
//   e = eb*16 + (lane&15), d = it*32 + (lane>>4)*8 + j.
// ---------------------------------------------------------------------------
__global__ __launch_bounds__(256) void kv_norm(const u16* __restrict__ partsT,
    const float* __restrict__ denom, u16* __restrict__ KV_nT)
{
  const int t = threadIdx.x;
  const int b = blockIdx.y;
  const int s4 = blockIdx.x*256 + t;        // us4 slot, 0..16383
  const int e0b = s4 >> 12;
  const int rem = s4 & 4095;
  const int comb = rem >> 6;                // w*16 + mi*4 + ei
  const int l = rem & 63;
  const int w  = comb >> 4;
  const int mi = (comb >> 2) & 3;
  const int ei = comb & 3;
  const int e  = e0b*64 + ei*16 + (l & 15);
  const int d0 = w*64 + mi*16 + (l >> 4)*4;

  const float dn = denom[b*256 + e];
  float s0=0.f,s1=0.f,s2=0.f,s3=0.f;
  #pragma unroll 4
  for (int nc=0;nc<16;nc++){
    us4 v = *(const us4*)&partsT[(size_t)(nc*16 + b)*65536 + (size_t)s4*4];
    s0+=bf2f(v[0]); s1+=bf2f(v[1]); s2+=bf2f(v[2]); s3+=bf2f(v[3]);
  }
  us4 o; o[0]=f2bf(s0/dn); o[1]=f2bf(s1/dn); o[2]=f2bf(s2/dn); o[3]=f2bf(s3/dn);

  const int eb  = e >> 4;
  const int i16 = e & 15;
  const int it  = d0 >> 5;
  const int qo  = (d0 >> 3) & 3;
  const int j0  = d0 & 4;
  *(us4*)&KV_nT[(size_t)b*65536 + (size_t)((eb*8 + it)*512 + (qo*16 + i16)*8 + j0)] = o;
}

// ---------------------------------------------------------------------------
// out_fused: per 64n x 256e block:
//   GEMM1: phi = sigmoid(Q@Wq+bq)  (A = Q tile staged in LDS, B = WqT frag)
//   rowsum computed block-locally (LDS atomics, no global pass)
//   phi -> sh.S (bf16), then
//   GEMM2: out = sigmoid(rs)/(rs+eps) * phi @ KV_n   (B = KVf frag, L2-hot)
// Deletes phi_q materialization (32MB write + 32MB read) and the phi q-pass.
// ---------------------------------------------------------------------------
__global__ __launch_bounds__(256, 3) void out_fused(
    const float* __restrict__ Q, const u16* __restrict__ WqT,
    const float* __restrict__ bq, const u16* __restrict__ KV_nT,
    float* __restrict__ outp)
{
  __shared__ union {
    u16 A[64][264];     // GEMM1 A staging (Q tile bf16)
    u16 S[64][264];     // phi tile [row][f] for GEMM2
  } sh;
  __shared__ float rs_sh[64];

  const int t = threadIdx.x;
  const int l = t & 63;
  const int wf = t >> 6;          // GEMM1: f-quarter; GEMM2: e-quarter
  const int i16 = l & 15, q = l >> 4;
  const int n0 = blockIdx.x * 64;
  const int b  = blockIdx.y;

  if (t < 64) rs_sh[t] = 0.f;

  // ---- stage Q tile (64x256 f32 -> bf16 LDS), 2 batches of 8 float4 ----
  {
    const int r0 = t >> 4;
    const int c0 = t & 15;
    const size_t gq = (size_t)(b*4096 + n0) * 256;
    #pragma unroll
    for (int half = 0; half < 2; half++) {
      float4 v[8];
      #pragma unroll
      for (int p = 0; p < 8; p++) {
        const int row = r0 + 16*(half*2 + (p >> 2));
        const int k4  = c0 + 16*(p & 3);
        v[p] = *(const float4*)&Q[gq + (size_t)row*256 + k4*4];
      }
      #pragma unroll
      for (int p = 0; p < 8; p++) {
        const int row = r0 + 16*(half*2 + (p >> 2));
        const int k4  = c0 + 16*(p & 3);
        *(us4*)&sh.A[row][k4*4] = cvt4(v[p]);
      }
    }
  }
  __syncthreads();

  // ---- GEMM1: phi = sigmoid(Q@Wq + bq) ----
  f32x4 acc[4][4];
  #pragma unroll
  for (int i=0;i<4;i++)
    #pragma unroll
    for (int j=0;j<4;j++) acc[i][j] = (f32x4){0.f,0.f,0.f,0.f};

  {
    const u16* wbf = WqT + (size_t)wf*16384 + (size_t)l*8;
    short8 Bfr[3][4];
    #pragma unroll
    for (int fi=0;fi<4;fi++) Bfr[0][fi] = *(const short8*)&wbf[fi*4096];
    #pragma unroll
    for (int fi=0;fi<4;fi++) Bfr[1][fi] = *(const short8*)&wbf[fi*4096 + 512];

    #pragma unroll
    for (int it = 0; it < 8; it++) {
      if (it < 6) {
        #pragma unroll
        for (int fi=0;fi<4;fi++)
          Bfr[(it+2)%3][fi] = *(const short8*)&wbf[fi*4096 + (it+2)*512];
      }
      short8 af[4];
      #pragma unroll
      for (int mi=0;mi<4;mi++)
        af[mi] = *(const short8*)&sh.A[mi*16 + i16][it*32 + q*8];
      #pragma unroll
      for (int mi=0;mi<4;mi++)
        #pragma unroll
        for (int fi=0;fi<4;fi++)
          acc[mi][fi] = __builtin_amdgcn_mfma_f32_16x16x32_bf16(af[mi], Bfr[it%3][fi], acc[mi][fi], 0,0,0);
    }
  }

  float bv[4];
  #pragma unroll
  for (int fi=0;fi<4;fi++) bv[fi] = bq[wf*64 + fi*16 + i16];

  __syncthreads();   // GEMM1 A reads done; LDS reusable for S

  // ---- epilogue1: sigmoid -> sh.S + block-local rowsum ----
  #pragma unroll
  for (int mi=0;mi<4;mi++) {
    float rsub[4] = {0.f,0.f,0.f,0.f};
    #pragma unroll
    for (int fi=0;fi<4;fi++) {
      #pragma unroll
      for (int r=0;r<4;r++) {
        float ph = sigmoidf_fast(acc[mi][fi][r] + bv[fi]);
        rsub[r] += ph;
        sh.S[mi*16 + q*4 + r][wf*64 + fi*16 + i16] = f2bf(ph);
      }
    }
    #pragma unroll
    for (int r=0;r<4;r++) {
      float s = rsub[r];
      s += __shfl_xor(s,1); s += __shfl_xor(s,2); s += __shfl_xor(s,4); s += __shfl_xor(s,8);
      if (i16 == 0) atomicAdd(&rs_sh[mi*16 + q*4 + r], s);
    }
  }

  // issue GEMM2 B prefetch before the barrier (independent of LDS)
  const u16* kbf = KV_nT + (size_t)b*65536 + (size_t)wf*16384 + (size_t)l*8;
  short8 Bfr2[3][4];
  #pragma unroll
  for (int ei=0;ei<4;ei++) Bfr2[0][ei] = *(const short8*)&kbf[ei*4096];
  #pragma unroll
  for (int ei=0;ei<4;ei++) Bfr2[1][ei] = *(const short8*)&kbf[ei*4096 + 512];

  __syncthreads();   // S + rs_sh ready

  // ---- GEMM2: out = gate * phi @ KV ----
  #pragma unroll
  for (int i=0;i<4;i++)
    #pragma unroll
    for (int j=0;j<4;j++) acc[i][j] = (f32x4){0.f,0.f,0.f,0.f};

  #pragma unroll
  for (int it=0; it<8; it++){
    if (it < 6) {
      #pragma unroll
      for (int ei=0;ei<4;ei++)
        Bfr2[(it+2)%3][ei] = *(const short8*)&kbf[ei*4096 + (it+2)*512];
    }
    short8 af[4];
    #pragma unroll
    for (int mi=0;mi<4;mi++)
      af[mi] = *(const short8*)&sh.S[mi*16 + i16][it*32 + q*8];
    #pragma unroll
    for (int mi=0;mi<4;mi++)
      #pragma unroll
      for (int ei=0;ei<4;ei++)
        acc[mi][ei] = __builtin_amdgcn_mfma_f32_16x16x32_bf16(af[mi], Bfr2[it%3][ei], acc[mi][ei],0,0,0);
  }

  #pragma unroll
  for (int mi=0;mi<4;mi++){
    #pragma unroll
    for (int r=0;r<4;r++){
      const int nl = mi*16 + q*4 + r;
      const float rs = rs_sh[nl];
      const float gate = sigmoidf_(rs) / (rs + EPS_);
      #pragma unroll
      for (int ei=0;ei<4;ei++)
        outp[((size_t)(b*4096 + n0 + nl))*256 + wf*64 + ei*16 + i16] = gate*acc[mi][ei][r];
    }
  }
}

extern "C" void kernel_launch(void* const* d_in, const int* in_sizes, int n_in,
                              void* d_out, int out_size, void* d_ws, size_t ws_size,
                              hipStream_t stream) {
  const float* Q  = (const float*)d_in[0];
  const float* K  = (const float*)d_in[1];
  const float* V  = (const float*)d_in[2];
  const float* Wq = (const float*)d_in[3];
  const float* bq = (const float*)d_in[4];
  const float* Wk = (const float*)d_in[5];
  const float* bk = (const float*)d_in[6];
  float* out = (float*)d_out;

  u16* phi_kT = (u16*)d_ws;                 // 16,777,216 bf16 TILED [b][nchunk][d][n64]
  u16* WqT    = phi_kT + 16777216;          // 65,536 (fragment order)
  u16* WkT    = WqT + 65536;                // 65,536 (fragment order)
  float* colsum = (float*)(WkT + 65536);    // 4096
  float* denom  = colsum + 4096;            // 4096
  u16* partsT = (u16*)(denom + 4096);       // 16*16*65536 bf16 (fragment-flat)
  u16* KV_nT  = partsT + 16777216;          // 1,048,576 bf16 (fragment order)

  hipMemsetAsync(colsum, 0, 8192 * sizeof(float), stream);

  prep_w<<<dim3(32), 256, 0, stream>>>(Wq, Wk, WqT, WkT);
  phi_k<<<dim3(1024), 256, 0, stream>>>(K, WkT, bk, phi_kT, colsum);
  kv_kernel<<<dim3(4, 16, 16), 256, 0, stream>>>(phi_kT, V, colsum, partsT, denom);
  kv_norm<<<dim3(64, 16), 256, 0, stream>>>(partsT, denom, KV_nT);
  out_fused<<<dim3(64, 16), 256, 0, stream>>>(Q, WqT, bq, KV_nT, out);
}